// Round 6
// baseline (191.026 us; speedup 1.0000x reference)
//
#include <hip/hip_runtime.h>
#include <math.h>

#define N_POSE   1024
#define M_TRAIN  10000
#define NJOINT   21
#define KNEIGH   5
#define CLIPV    (1.0f - 1e-7f)
#define PI_F     3.14159265358979f
#define BIGF     1e30f
#define MB       5        // train poses per accumulator block (keeps live VGPRs ~50)
#define TPB      256      // 4 waves/block share one LDS train tile
#define ROWGRP   (N_POSE / TPB)          // 4 row-groups
#define QN_FLOATS (N_POSE * NJOINT * 4)  // normalized-pose staging in ws

// A&S 4.4.45 poly (abs err ~1.8e-4) with raw v_sqrt_f32 (no ocml fixup code)
__device__ __forceinline__ float acos_fast(float d) {
    float a = fminf(fabsf(d), CLIPV);
    float p = fmaf(a, -0.0187293f, 0.0742610f);
    p = fmaf(a, p, -0.2121144f);
    p = fmaf(a, p, 1.5707288f);
    float r = __builtin_amdgcn_sqrtf(1.0f - a) * p;
    return (d >= 0.0f) ? r : (PI_F - r);
}

// one-shot: normalize all query quats so the hot loop has no rsqrt
__global__ __launch_bounds__(256)
void pose_norm_kernel(const float* __restrict__ pose, float* __restrict__ qn) {
    int i = blockIdx.x * blockDim.x + threadIdx.x;
    if (i >= N_POSE * NJOINT) return;
    float4 v = ((const float4*)pose)[i];
    float inv = rsqrtf(v.x * v.x + v.y * v.y + v.z * v.z + v.w * v.w);
    v.x *= inv; v.y *= inv; v.z *= inv; v.w *= inv;
    ((float4*)qn)[i] = v;
}

// thread = query row. The block's m-chunk of train poses is staged ONCE into
// LDS; hot-loop train reads are wave-uniform ds_read_b128 -> broadcast
// (16 B/wave, conflict-free, no scalar cache). j-outer / m-inner with MB=5
// accumulators: peak live state ~50 VGPR -> no spills at the 64-VGPR budget.
__global__ __launch_bounds__(TPB)
void pose_dist_kernel(const float* __restrict__ qn,
                      const float* __restrict__ train,
                      float* __restrict__ topk,
                      int chunks, int mchunk) {
    extern __shared__ float4 tile[];      // mchunk * NJOINT float4s
    const int nb = blockIdx.x / chunks;   // row-group
    const int cb = blockIdx.x % chunks;   // m-chunk
    const int t  = threadIdx.x;
    const int n  = nb * TPB + t;

    // cooperative stage: chunk's train poses -> LDS (coalesced float4 copy)
    {
        const float4* __restrict__ g = (const float4*)train + (size_t)cb * mchunk * NJOINT;
        const int nquat = mchunk * NJOINT;
        for (int i = t; i < nquat; i += TPB) tile[i] = g[i];
    }
    __syncthreads();

    const float4* __restrict__ qp = (const float4*)qn + (size_t)n * NJOINT;
    float t0 = BIGF, t1 = BIGF, t2 = BIGF, t3 = BIGF, t4 = BIGF;

#pragma unroll 1
    for (int mb = 0; mb < mchunk; mb += MB) {
        float acc[MB];
#pragma unroll
        for (int k = 0; k < MB; ++k) acc[k] = 0.f;

        float4 qc = qp[0];
#pragma unroll 1
        for (int j = 0; j < NJOINT; ++j) {
            float4 qnx = qp[(j + 1 < NJOINT) ? j + 1 : 0];   // prefetch next joint
            const float4* __restrict__ uj = tile + (size_t)mb * NJOINT + j;
#pragma unroll
            for (int mm = 0; mm < MB; ++mm) {
                float4 u = uj[(size_t)mm * NJOINT];          // uniform -> broadcast
                float d = u.x * qc.x + u.y * qc.y + u.z * qc.z + u.w * qc.w;
                acc[mm] += acos_fast(d);
            }
            qc = qnx;
        }
#pragma unroll
        for (int mm = 0; mm < MB; ++mm) {
            float v = acc[mm] * 0.5f;
            t4 = fminf(t4, fmaxf(t3, v));
            t3 = fminf(t3, fmaxf(t2, v));
            t2 = fminf(t2, fmaxf(t1, v));
            t1 = fminf(t1, fmaxf(t0, v));
            t0 = fminf(t0, v);
        }
    }

    float* w = topk + ((size_t)n * chunks + cb) * KNEIGH;
    w[0] = t0; w[1] = t1; w[2] = t2; w[3] = t3; w[4] = t4;
}

// one wave per query row: merge chunks*5 candidates -> mean of top-5
__global__ __launch_bounds__(64)
void pose_reduce_kernel(const float* __restrict__ topk, float* __restrict__ out,
                        int chunks) {
    const int n = blockIdx.x;
    const int lane = threadIdx.x;
    const int total = chunks * KNEIGH;
    const float* __restrict__ w = topk + (size_t)n * total;

    float t0 = BIGF, t1 = BIGF, t2 = BIGF, t3 = BIGF, t4 = BIGF;
    for (int i = lane; i < total; i += 64) {
        float v = w[i];
        t4 = fminf(t4, fmaxf(t3, v));
        t3 = fminf(t3, fmaxf(t2, v));
        t2 = fminf(t2, fmaxf(t1, v));
        t1 = fminf(t1, fmaxf(t0, v));
        t0 = fminf(t0, v);
    }

    float sum = 0.f;
#pragma unroll
    for (int r = 0; r < KNEIGH; ++r) {
        float v = t0; int who = lane;
        for (int off = 32; off; off >>= 1) {
            float ov = __shfl_xor(v, off);
            int   ow = __shfl_xor(who, off);
            if (ov < v || (ov == v && ow < who)) { v = ov; who = ow; }
        }
        sum += v;
        if (lane == who) { t0 = t1; t1 = t2; t2 = t3; t3 = t4; t4 = BIGF; }
    }
    if (lane == 0) out[n] = sum * (1.0f / KNEIGH);
}

extern "C" void kernel_launch(void* const* d_in, const int* in_sizes, int n_in,
                              void* d_out, int out_size, void* d_ws, size_t ws_size,
                              hipStream_t stream) {
    const float* pose  = (const float*)d_in[0];
    const float* train = (const float*)d_in[1];
    float* out  = (float*)d_out;
    float* qn   = (float*)d_ws;                 // QN_FLOATS floats
    float* topk = (float*)d_ws + QN_FLOATS;

    // largest chunk tier whose topk fits ws (tiers divide 10000; mchunk % 5 == 0)
    size_t base = (size_t)QN_FLOATS * sizeof(float);
    int chunks = 250;
    if (base + (size_t)N_POSE * chunks * KNEIGH * sizeof(float) > ws_size) chunks = 125;
    if (base + (size_t)N_POSE * chunks * KNEIGH * sizeof(float) > ws_size) chunks = 50;
    if (base + (size_t)N_POSE * chunks * KNEIGH * sizeof(float) > ws_size) chunks = 10;
    const int mchunk = M_TRAIN / chunks;
    const size_t lds_bytes = (size_t)mchunk * NJOINT * sizeof(float4);

    pose_norm_kernel<<<dim3((N_POSE * NJOINT + 255) / 256), dim3(256), 0, stream>>>(pose, qn);

    dim3 grid1(ROWGRP * chunks);
    pose_dist_kernel<<<grid1, dim3(TPB), lds_bytes, stream>>>(qn, train, topk, chunks, mchunk);

    pose_reduce_kernel<<<dim3(N_POSE), dim3(64), 0, stream>>>(topk, out, chunks);
}

// Round 7
// 106.970 us; speedup vs baseline: 1.7858x; 1.7858x over previous
//
#include <hip/hip_runtime.h>
#include <math.h>

#define N_POSE   1024
#define M_TRAIN  10000
#define NJOINT   21
#define KNEIGH   5
#define CLIPV    (1.0f - 1e-7f)
#define PI_F     3.14159265358979f
#define HPI_F    1.57079632679490f
#define BIGF     1e30f
#define QN_FLOATS (N_POSE * NJOINT * 4)  // normalized-pose staging in ws

// one-shot: normalize all query quats so the hot loop has no rsqrt
__global__ __launch_bounds__(256)
void pose_norm_kernel(const float* __restrict__ pose, float* __restrict__ qn) {
    int i = blockIdx.x * blockDim.x + threadIdx.x;
    if (i >= N_POSE * NJOINT) return;
    float4 v = ((const float4*)pose)[i];
    float inv = rsqrtf(v.x * v.x + v.y * v.y + v.z * v.z + v.w * v.w);
    v.x *= inv; v.y *= inv; v.z *= inv; v.w *= inv;
    ((float4*)qn)[i] = v;
}

// thread = query row; q[21] pinned live in VGPRs via opaque asm (no remat, no
// spill). Train reads wave-uniform -> scalarized s_load (SGPRs), j fully
// unrolled so loads issue early. acos via A&S poly + copysign fold:
//   acos(d) = pi/2 - copysign(pi/2 - sqrt(1-a)*p, d),  a = min(|d|,CLIP)
//   sum_j acos = 21*pi/2 - sum_j copysign(...)
__global__ __launch_bounds__(64)
void pose_dist_kernel(const float* __restrict__ qn,
                      const float* __restrict__ train,
                      float* __restrict__ topk,
                      int chunks, int mchunk) {
    const int nb = blockIdx.x / chunks;   // query group (0..15)
    const int cb = blockIdx.x % chunks;   // m-chunk
    const int n  = nb * 64 + threadIdx.x;

    float4 q[NJOINT];
    const float4* __restrict__ qp = (const float4*)qn + (size_t)n * NJOINT;
#pragma unroll
    for (int j = 0; j < NJOINT; ++j) q[j] = qp[j];
    // pin all 84 components live in VGPRs: compiler cannot rematerialize
#pragma unroll
    for (int j = 0; j < NJOINT; ++j)
        asm volatile("" : "+v"(q[j].x), "+v"(q[j].y), "+v"(q[j].z), "+v"(q[j].w));

    float t0 = BIGF, t1 = BIGF, t2 = BIGF, t3 = BIGF, t4 = BIGF;
    const float4* __restrict__ tq = (const float4*)train + (size_t)cb * mchunk * NJOINT;

#pragma unroll 1
    for (int mi = 0; mi < mchunk; ++mi) {
        const float4* __restrict__ tm = tq + (size_t)mi * NJOINT;
        float a0 = 0.f, a1 = 0.f;     // two chains of copysign terms
#pragma unroll
        for (int j = 0; j < NJOINT; ++j) {
            float4 p = q[j];
            float4 u = tm[j];                         // wave-uniform -> s_load
            float d = u.x * p.x + u.y * p.y + u.z * p.z + u.w * p.w;
            float a = fminf(fabsf(d), CLIPV);
            float pl = fmaf(a, -0.0187293f, 0.0742610f);
            pl = fmaf(a, pl, -0.2121144f);
            pl = fmaf(a, pl, 1.5707288f);
            float r  = __builtin_amdgcn_sqrtf(1.0f - a) * pl;
            float cs = __builtin_copysignf(HPI_F - r, d);
            if (j & 1) a1 += cs; else a0 += cs;
        }
        float v = (NJOINT * HPI_F - (a0 + a1)) * 0.5f;
        t4 = fminf(t4, fmaxf(t3, v));
        t3 = fminf(t3, fmaxf(t2, v));
        t2 = fminf(t2, fmaxf(t1, v));
        t1 = fminf(t1, fmaxf(t0, v));
        t0 = fminf(t0, v);
    }

    float* w = topk + ((size_t)n * chunks + cb) * KNEIGH;
    w[0] = t0; w[1] = t1; w[2] = t2; w[3] = t3; w[4] = t4;
}

// one wave per query row: merge chunks*5 candidates -> mean of top-5
__global__ __launch_bounds__(64)
void pose_reduce_kernel(const float* __restrict__ topk, float* __restrict__ out,
                        int chunks) {
    const int n = blockIdx.x;
    const int lane = threadIdx.x;
    const int total = chunks * KNEIGH;
    const float* __restrict__ w = topk + (size_t)n * total;

    float t0 = BIGF, t1 = BIGF, t2 = BIGF, t3 = BIGF, t4 = BIGF;
    for (int i = lane; i < total; i += 64) {
        float v = w[i];
        t4 = fminf(t4, fmaxf(t3, v));
        t3 = fminf(t3, fmaxf(t2, v));
        t2 = fminf(t2, fmaxf(t1, v));
        t1 = fminf(t1, fmaxf(t0, v));
        t0 = fminf(t0, v);
    }

    float sum = 0.f;
#pragma unroll
    for (int r = 0; r < KNEIGH; ++r) {
        float v = t0; int who = lane;
        for (int off = 32; off; off >>= 1) {
            float ov = __shfl_xor(v, off);
            int   ow = __shfl_xor(who, off);
            if (ov < v || (ov == v && ow < who)) { v = ov; who = ow; }
        }
        sum += v;
        if (lane == who) { t0 = t1; t1 = t2; t2 = t3; t3 = t4; t4 = BIGF; }
    }
    if (lane == 0) out[n] = sum * (1.0f / KNEIGH);
}

extern "C" void kernel_launch(void* const* d_in, const int* in_sizes, int n_in,
                              void* d_out, int out_size, void* d_ws, size_t ws_size,
                              hipStream_t stream) {
    const float* pose  = (const float*)d_in[0];
    const float* train = (const float*)d_in[1];
    float* out  = (float*)d_out;
    float* qn   = (float*)d_ws;                 // QN_FLOATS floats
    float* topk = (float*)d_ws + QN_FLOATS;

    // largest chunk tier whose topk fits ws (tiers divide 10000)
    size_t base = (size_t)QN_FLOATS * sizeof(float);
    int chunks = 250;
    if (base + (size_t)N_POSE * chunks * KNEIGH * sizeof(float) > ws_size) chunks = 125;
    if (base + (size_t)N_POSE * chunks * KNEIGH * sizeof(float) > ws_size) chunks = 50;
    if (base + (size_t)N_POSE * chunks * KNEIGH * sizeof(float) > ws_size) chunks = 10;
    const int mchunk = M_TRAIN / chunks;

    pose_norm_kernel<<<dim3((N_POSE * NJOINT + 255) / 256), dim3(256), 0, stream>>>(pose, qn);

    dim3 grid1((N_POSE / 64) * chunks);
    pose_dist_kernel<<<grid1, dim3(64), 0, stream>>>(qn, train, topk, chunks, mchunk);

    pose_reduce_kernel<<<dim3(N_POSE), dim3(64), 0, stream>>>(topk, out, chunks);
}